// Round 7
// baseline (403.861 us; speedup 1.0000x reference)
//
#include <hip/hip_runtime.h>
#include <hip/hip_bf16.h>

// ---------- types ----------
typedef unsigned short u16;
typedef unsigned int u32;
typedef float f32x4 __attribute__((ext_vector_type(4)));
typedef float f32x16 __attribute__((ext_vector_type(16)));
typedef _Float16 f16x8 __attribute__((ext_vector_type(8)));
typedef u32 u32x4 __attribute__((ext_vector_type(4)));
typedef u32 u32x2 __attribute__((ext_vector_type(2)));

#define SEQ 2048
#define EDIM 1024

__device__ __forceinline__ u16 f2h(float f) {
  _Float16 h = (_Float16)f;
  return __builtin_bit_cast(u16, h);
}
__device__ __forceinline__ float h2f(u16 u) {
  return (float)__builtin_bit_cast(_Float16, u);
}
__device__ __forceinline__ u32 pk(float a, float b) {
  return (u32)f2h(a) | ((u32)f2h(b) << 16);
}

// ---------- fused fp32 -> fp16 convert for all 4 inputs, 8 elems/thread ----
#define N_X  2097152
#define N_WP 327680
#define N_W1 131072
#define N_W2 131072
__global__ __launch_bounds__(256) void cvt_all(const float* __restrict__ x, u16* __restrict__ xb,
                                               const float* __restrict__ wp, u16* __restrict__ wpb,
                                               const float* __restrict__ w1, u16* __restrict__ w1b,
                                               const float* __restrict__ w2, u16* __restrict__ w2b) {
  int i = blockIdx.x * 256 + threadIdx.x;
  const float* src; u16* dst; int li;
  if (i < N_X) { src = x; dst = xb; li = i; }
  else if (i < N_X + N_WP) { src = wp; dst = wpb; li = i - N_X; }
  else if (i < N_X + N_WP + N_W1) { src = w1; dst = w1b; li = i - N_X - N_WP; }
  else if (i < N_X + N_WP + N_W1 + N_W2) { src = w2; dst = w2b; li = i - N_X - N_WP - N_W1; }
  else return;
  const f32x4* p = (const f32x4*)(src + (size_t)li * 8);
  f32x4 a = p[0], b = p[1];
  u32x4 o = {pk(a[0], a[1]), pk(a[2], a[3]), pk(b[0], b[1]), pk(b[2], b[3])};
  *(u32x4*)(dst + (size_t)li * 8) = o;
}

struct GemmP {
  const u16* A; const u16* B;
  int lda, ldb, K;
  long bsA, bsB, bsC;       // per-blockIdx.z element strides
  int ldc;
  u16* Cb;                  // EPI 2/3/4 (f16 store)
  const float* bias;        // EPI 2,3
  const u16* resid;         // EPI 3 (h, f16, ld 512)
  u16* qk; u16* vT;         // EPI 1 (proj split)
  float scale;              // EPI 1
};

// =======================================================================
// 128x128 tile, BK=64, 4 waves (2x2), 32x32x16 f16 MFMA.
// COVERED-STAGING single-barrier double-buffer loop (guide T3-minimum):
//   per K-tile: __syncthreads (drains this tile's staging, issued one
//   iteration ago and covered by that iteration's reads+MFMA) ->
//   stage(next tile, other buffer) -> 16 ds_read_b128 -> 16 MFMA(32x32).
// One barrier per K-tile; staging latency hidden under compute.
// LDS 64KB (2 x (A16K + B16K)); swizzle identical to the measured-0-
// conflict layout (slot ^= row&7 on 16B slots of 128B rows).
// Per-wave 64x64 = 2x2 tiles of 32x32; acc 2x2 x f32x16.
// A/B frag: row = lane&31, k = 8*(lane>>5)+j (K=16 per step).
// C/D: col = lane&31, row = (r&3) + 8*(r>>2) + 4*(lane>>5)  [m74].
// EPI: 1 = proj split (q*SC | k | vT), 2 = +bias relu f16 (ff1),
//      3 = +bias +resid f16 (ff2), 4 = plain f16 (scores, PV).
// =======================================================================
template <int EPI>
__global__ __launch_bounds__(256) void gemm_bt(GemmP p) {
  __shared__ __align__(16) char lds[65536];
  const int tid = threadIdx.x;
  const int lane = tid & 63;
  const int wave = tid >> 6;
  const int wm = wave >> 1, wn = wave & 1;
  const int bn0 = blockIdx.x * 128;
  const int bm0 = blockIdx.y * 128;
  const int z = blockIdx.z;

  // --- staging state: 4 A-chunks + 4 B-chunks per thread, ptr-advance ---
  const u16* gA[4]; const u16* gB[4];
  int ldsA[4], ldsB[4];
  {
    const u16* Ab = p.A + (long)z * p.bsA + (long)bm0 * p.lda;
    const u16* Bb = p.B + (long)z * p.bsB + (long)bn0 * p.ldb;
#pragma unroll
    for (int i = 0; i < 4; ++i) {
      int ch = i * 256 + tid;
      int row = ch >> 3, s = ch & 7;
      int ks = ((s ^ (row & 7)) << 3);  // inverse-swizzled global source
      gA[i] = Ab + (long)row * p.lda + ks;
      gB[i] = Bb + (long)row * p.ldb + ks;
      ldsA[i] = ch * 16;
      ldsB[i] = 16384 + ch * 16;
    }
  }
  auto stage = [&](int buf) {
    char* dst = lds + buf * 32768;
#pragma unroll
    for (int i = 0; i < 4; ++i) {
      __builtin_amdgcn_global_load_lds(
          (const __attribute__((address_space(1))) u32*)gA[i],
          (__attribute__((address_space(3))) u32*)(dst + ldsA[i]), 16, 0, 0);
      gA[i] += 64;
    }
#pragma unroll
    for (int i = 0; i < 4; ++i) {
      __builtin_amdgcn_global_load_lds(
          (const __attribute__((address_space(1))) u32*)gB[i],
          (__attribute__((address_space(3))) u32*)(dst + ldsB[i]), 16, 0, 0);
      gB[i] += 64;
    }
  };

  // --- LDS fragment read offsets: [m/n-tile][ks], 32x32x16 frags ---
  int aoff[2][4], boff[2][4];
#pragma unroll
  for (int i = 0; i < 2; ++i) {
    int rA = wm * 64 + i * 32 + (lane & 31);
    int rB = wn * 64 + i * 32 + (lane & 31);
#pragma unroll
    for (int ks = 0; ks < 4; ++ks) {
      aoff[i][ks] = rA * 128 + ((((ks << 1) | (lane >> 5)) ^ (rA & 7)) << 4);
      boff[i][ks] = 16384 + rB * 128 + ((((ks << 1) | (lane >> 5)) ^ (rB & 7)) << 4);
    }
  }

  f32x16 acc[2][2] = {};
  stage(0);
  const int nk = p.K >> 6;
  int cur = 0;
  for (int kt = 0; kt < nk; ++kt) {
    __syncthreads();                  // buf[cur] staged & visible (drain covered)
    if (kt + 1 < nk) stage(cur ^ 1);  // issue next tile FIRST -> hidden under MFMA
    const char* base = lds + cur * 32768;
#pragma unroll
    for (int ks = 0; ks < 4; ++ks) {
      f16x8 a0 = *(const f16x8*)(base + aoff[0][ks]);
      f16x8 a1 = *(const f16x8*)(base + aoff[1][ks]);
      f16x8 b0 = *(const f16x8*)(base + boff[0][ks]);
      f16x8 b1 = *(const f16x8*)(base + boff[1][ks]);
      acc[0][0] = __builtin_amdgcn_mfma_f32_32x32x16_f16(a0, b0, acc[0][0], 0, 0, 0);
      acc[0][1] = __builtin_amdgcn_mfma_f32_32x32x16_f16(a0, b1, acc[0][1], 0, 0, 0);
      acc[1][0] = __builtin_amdgcn_mfma_f32_32x32x16_f16(a1, b0, acc[1][0], 0, 0, 0);
      acc[1][1] = __builtin_amdgcn_mfma_f32_32x32x16_f16(a1, b1, acc[1][1], 0, 0, 0);
    }
    cur ^= 1;
  }

  // ---- epilogue: per tile (i,j), reg r: row=(r&3)+8*(r>>2)+4*(lane>>5),
  //      col=lane&31 ----
#pragma unroll
  for (int i = 0; i < 2; ++i) {
#pragma unroll
    for (int j = 0; j < 2; ++j) {
      int nn = bn0 + wn * 64 + j * 32 + (lane & 31);
#pragma unroll
      for (int rq = 0; rq < 4; ++rq) {
        int mrow = bm0 + wm * 64 + i * 32 + rq * 8 + ((lane >> 5) << 2);
        float v0 = acc[i][j][rq * 4 + 0], v1 = acc[i][j][rq * 4 + 1];
        float v2 = acc[i][j][rq * 4 + 2], v3 = acc[i][j][rq * 4 + 3];
        if constexpr (EPI == 1) {  // proj split into q*SCALE | k | vT
          int b = mrow >> 11, l0 = mrow & 2047;
          if (nn < EDIM) {
            u16* dst = p.qk + (long)b * 4194304 + (long)l0 * 1024 + nn;
            dst[0] = f2h(v0 * p.scale); dst[1024] = f2h(v1 * p.scale);
            dst[2048] = f2h(v2 * p.scale); dst[3072] = f2h(v3 * p.scale);
          } else if (nn < 2 * EDIM) {
            u16* dst = p.qk + (long)b * 4194304 + 2097152 + (long)l0 * 1024 + (nn - EDIM);
            dst[0] = f2h(v0); dst[1024] = f2h(v1);
            dst[2048] = f2h(v2); dst[3072] = f2h(v3);
          } else {  // vT[b][nn-2048][l0..l0+3] -- 8B packed store
            u16* dst = p.vT + (long)b * 1048576 + (long)(nn - 2 * EDIM) * 2048 + l0;
            u32x2 w = {pk(v0, v1), pk(v2, v3)};
            *(u32x2*)dst = w;
          }
        } else if constexpr (EPI == 2) {  // +bias, relu, f16 out (ff1)
          float bias = p.bias[nn];
          u16* dst = p.Cb + (long)mrow * p.ldc + nn;
          dst[0] = f2h(fmaxf(v0 + bias, 0.f));
          dst[p.ldc] = f2h(fmaxf(v1 + bias, 0.f));
          dst[2 * p.ldc] = f2h(fmaxf(v2 + bias, 0.f));
          dst[3 * p.ldc] = f2h(fmaxf(v3 + bias, 0.f));
        } else if constexpr (EPI == 3) {  // +bias +resid, f16 out (ff2)
          float bias = p.bias[nn];
          u16* dst = p.Cb + (long)mrow * 512 + nn;
          const u16* rs = p.resid + (long)mrow * 512 + nn;
          dst[0] = f2h(v0 + bias + h2f(rs[0]));
          dst[512] = f2h(v1 + bias + h2f(rs[512]));
          dst[1024] = f2h(v2 + bias + h2f(rs[1024]));
          dst[1536] = f2h(v3 + bias + h2f(rs[1536]));
        } else {  // EPI 4: plain f16 (scores, PV)
          u16* dst = p.Cb + (long)z * p.bsC + (long)mrow * p.ldc + nn;
          dst[0] = f2h(v0); dst[p.ldc] = f2h(v1);
          dst[2 * p.ldc] = f2h(v2); dst[3 * p.ldc] = f2h(v3);
        }
      }
    }
  }
}

// ---------- row softmax: 1 block / row of 2048 f16 -> f16 weights ----------
__global__ __launch_bounds__(256) void softmax_rows(const u16* __restrict__ S,
                                                    u16* __restrict__ W, int b0) {
  int r = blockIdx.x;
  int z = r >> 11, l = r & 2047;
  int tid = threadIdx.x, lane = tid & 63, wv = tid >> 6;
  const u16* x = S + (long)r * 2048 + tid * 8;
  u32x4 raw = *(const u32x4*)x;
  float e[8];
#pragma unroll
  for (int q = 0; q < 4; ++q) {
    e[2 * q] = h2f((u16)(raw[q] & 0xffff));
    e[2 * q + 1] = h2f((u16)(raw[q] >> 16));
  }
  float m = e[0];
#pragma unroll
  for (int q = 1; q < 8; ++q) m = fmaxf(m, e[q]);
#pragma unroll
  for (int off = 32; off; off >>= 1) m = fmaxf(m, __shfl_xor(m, off));
  __shared__ float red[8];
  if (lane == 0) red[wv] = m;
  __syncthreads();
  m = fmaxf(fmaxf(red[0], red[1]), fmaxf(red[2], red[3]));
  float s = 0.f;
#pragma unroll
  for (int q = 0; q < 8; ++q) { e[q] = __expf(e[q] - m); s += e[q]; }
#pragma unroll
  for (int off = 32; off; off >>= 1) s += __shfl_xor(s, off);
  if (lane == 0) red[4 + wv] = s;
  __syncthreads();
  s = red[4] + red[5] + red[6] + red[7];
  float inv = 1.f / s;
  u32x4 o = {pk(e[0] * inv, e[1] * inv), pk(e[2] * inv, e[3] * inv),
             pk(e[4] * inv, e[5] * inv), pk(e[6] * inv, e[7] * inv)};
  *(u32x4*)(W + (long)(b0 + z) * 4194304 + (long)l * 2048 + tid * 8) = o;
}

// ---------- LayerNorm over 512, wave per row ----------
template <int INF16, int OUTF16>
__global__ __launch_bounds__(256) void ln_rows(const void* __restrict__ X,
                                               const float* __restrict__ g,
                                               const float* __restrict__ bb,
                                               void* __restrict__ out) {
  int row = blockIdx.x * 4 + (threadIdx.x >> 6);
  int lane = threadIdx.x & 63;
  float v[8];
  if constexpr (INF16) {
    u32x4 raw = *(const u32x4*)((const u16*)X + (long)row * 512 + lane * 8);
#pragma unroll
    for (int q = 0; q < 4; ++q) {
      v[2 * q] = h2f((u16)(raw[q] & 0xffff));
      v[2 * q + 1] = h2f((u16)(raw[q] >> 16));
    }
  } else {
    const float* x = (const float*)X + (long)row * 512 + lane * 8;
    f32x4 a = *(const f32x4*)x, b = *(const f32x4*)(x + 4);
#pragma unroll
    for (int q = 0; q < 4; ++q) { v[q] = a[q]; v[4 + q] = b[q]; }
  }
  float s = 0.f, sq = 0.f;
#pragma unroll
  for (int q = 0; q < 8; ++q) { s += v[q]; sq += v[q] * v[q]; }
#pragma unroll
  for (int off = 32; off; off >>= 1) {
    s += __shfl_xor(s, off);
    sq += __shfl_xor(sq, off);
  }
  float mean = s * (1.f / 512.f);
  float var = sq * (1.f / 512.f) - mean * mean;
  float rstd = rsqrtf(var + 1e-5f);
  f32x4 g0 = *(const f32x4*)(g + lane * 8), g1v = *(const f32x4*)(g + lane * 8 + 4);
  f32x4 b0 = *(const f32x4*)(bb + lane * 8), b1v = *(const f32x4*)(bb + lane * 8 + 4);
  float o[8];
#pragma unroll
  for (int q = 0; q < 4; ++q) o[q] = (v[q] - mean) * rstd * g0[q] + b0[q];
#pragma unroll
  for (int q = 0; q < 4; ++q) o[4 + q] = (v[4 + q] - mean) * rstd * g1v[q] + b1v[q];
  if constexpr (OUTF16) {
    u32x4 pkd = {pk(o[0], o[1]), pk(o[2], o[3]), pk(o[4], o[5]), pk(o[6], o[7])};
    *(u32x4*)((u16*)out + (long)row * 512 + lane * 8) = pkd;
  } else {
    float* dst = (float*)out + (long)row * 512 + lane * 8;
    *(f32x4*)dst = (f32x4){o[0], o[1], o[2], o[3]};
    *(f32x4*)(dst + 4) = (f32x4){o[4], o[5], o[6], o[7]};
  }
}

// ---------- launch ----------
extern "C" void kernel_launch(void* const* d_in, const int* in_sizes, int n_in,
                              void* d_out, int out_size, void* d_ws, size_t ws_size,
                              hipStream_t stream) {
  const float* x = (const float*)d_in[0];
  const float* wp = (const float*)d_in[1];
  const float* w1 = (const float*)d_in[2];
  const float* b1 = (const float*)d_in[3];
  const float* w2 = (const float*)d_in[4];
  const float* b2 = (const float*)d_in[5];
  const float* g1 = (const float*)d_in[6];
  const float* be1 = (const float*)d_in[7];
  const float* g2 = (const float*)d_in[8];
  const float* be2 = (const float*)d_in[9];

  char* ws = (char*)d_ws;
  size_t off = 0;
  auto alloc = [&](size_t bytes) {
    char* p = ws + off;
    off += (bytes + 255) & ~(size_t)255;
    return p;
  };
  u16* wpb = (u16*)alloc(2560 * 1024 * 2);
  u16* w1b = (u16*)alloc(2048 * 512 * 2);
  u16* w2b = (u16*)alloc(512 * 2048 * 2);
  char* xb_region = alloc(33554432);            // x f16 -> attn_out f16
  u16* qk = (u16*)alloc(67108864);              // [q|k] f16 -> attnw -> ff1
  u16* vT = (u16*)alloc(16777216);              // v transposed f16
  u16* hb = (u16*)alloc(16777216);              // h f16
  int bpl = (ws_size >= off + (size_t)67108864) ? 8 : 4;
  char* sc_region = alloc((size_t)bpl * 2048 * 2048 * 2);
  if (off > ws_size) return;

  u16* xb = (u16*)xb_region;
  u16* attn16 = (u16*)xb_region;
  u16* scores = (u16*)sc_region;
  u16* y16 = (u16*)sc_region;
  u16* ff1 = qk;

  const float SC = (float)(0.03125 * 2.0 * 7.6246189861593985);

  cvt_all<<<dim3(10496), dim3(256), 0, stream>>>(x, xb, wp, wpb, w1, w1b, w2, w2b);

  {  // proj: (16384x1024) @ (2560x1024)^T, split epilogue
    GemmP p{};
    p.A = xb; p.lda = 1024; p.B = wpb; p.ldb = 1024; p.K = 1024;
    p.qk = qk; p.vT = vT; p.scale = SC;
    gemm_bt<1><<<dim3(20, 128, 1), 256, 0, stream>>>(p);
  }

  for (int it = 0; it < 8 / bpl; ++it) {  // scores + softmax
    int b0 = it * bpl;
    GemmP p{};
    p.A = qk + (long)b0 * 4194304; p.lda = 1024; p.bsA = 4194304;
    p.B = qk + (long)b0 * 4194304 + 2097152; p.ldb = 1024; p.bsB = 4194304;
    p.K = 1024; p.Cb = scores; p.ldc = 2048; p.bsC = 4194304;
    gemm_bt<4><<<dim3(16, 16, bpl), 256, 0, stream>>>(p);
    softmax_rows<<<dim3(bpl * 2048), dim3(256), 0, stream>>>(scores, qk, b0);
  }

  {  // PV: attnw(2048x2048) @ vT(512x2048)^T per batch -> f16
    GemmP p{};
    p.A = qk; p.lda = 2048; p.bsA = 4194304;
    p.B = vT; p.ldb = 2048; p.bsB = 1048576;
    p.K = 2048; p.Cb = attn16; p.ldc = 512; p.bsC = 1048576;
    gemm_bt<4><<<dim3(4, 16, 8), 256, 0, stream>>>(p);
  }

  ln_rows<1, 1><<<dim3(4096), dim3(256), 0, stream>>>(attn16, g1, be1, hb);

  {  // ff1: h(16384x512) @ w1(2048x512)^T, +b1 relu -> f16
    GemmP p{};
    p.A = hb; p.lda = 512; p.B = w1b; p.ldb = 512; p.K = 512;
    p.Cb = ff1; p.ldc = 2048; p.bias = b1;
    gemm_bt<2><<<dim3(16, 128, 1), 256, 0, stream>>>(p);
  }

  {  // ff2: ff1(16384x2048) @ w2(512x2048)^T, +b2 +h -> f16
    GemmP p{};
    p.A = ff1; p.lda = 2048; p.B = w2b; p.ldb = 2048; p.K = 2048;
    p.Cb = y16; p.bias = b2; p.resid = hb;
    gemm_bt<3><<<dim3(4, 128, 1), 256, 0, stream>>>(p);
  }

  ln_rows<1, 0><<<dim3(4096), dim3(256), 0, stream>>>(y16, g2, be2, (float*)d_out);
}

// Round 8
// 379.115 us; speedup vs baseline: 1.0653x; 1.0653x over previous
//
#include <hip/hip_runtime.h>
#include <hip/hip_bf16.h>

// ---------- types ----------
typedef unsigned short u16;
typedef unsigned int u32;
typedef float f32x4 __attribute__((ext_vector_type(4)));
typedef _Float16 f16x8 __attribute__((ext_vector_type(8)));
typedef u32 u32x4 __attribute__((ext_vector_type(4)));
typedef u32 u32x2 __attribute__((ext_vector_type(2)));

#define SEQ 2048
#define EDIM 1024

__device__ __forceinline__ u16 f2h(float f) {
  _Float16 h = (_Float16)f;
  return __builtin_bit_cast(u16, h);
}
__device__ __forceinline__ float h2f(u16 u) {
  return (float)__builtin_bit_cast(_Float16, u);
}
__device__ __forceinline__ u32 pk(float a, float b) {
  return (u32)f2h(a) | ((u32)f2h(b) << 16);
}

// ---------- fused fp32 -> fp16 convert for all 4 inputs, 8 elems/thread ----
#define N_X  2097152
#define N_WP 327680
#define N_W1 131072
#define N_W2 131072
__global__ __launch_bounds__(256) void cvt_all(const float* __restrict__ x, u16* __restrict__ xb,
                                               const float* __restrict__ wp, u16* __restrict__ wpb,
                                               const float* __restrict__ w1, u16* __restrict__ w1b,
                                               const float* __restrict__ w2, u16* __restrict__ w2b) {
  int i = blockIdx.x * 256 + threadIdx.x;
  const float* src; u16* dst; int li;
  if (i < N_X) { src = x; dst = xb; li = i; }
  else if (i < N_X + N_WP) { src = wp; dst = wpb; li = i - N_X; }
  else if (i < N_X + N_WP + N_W1) { src = w1; dst = w1b; li = i - N_X - N_WP; }
  else if (i < N_X + N_WP + N_W1 + N_W2) { src = w2; dst = w2b; li = i - N_X - N_WP - N_W1; }
  else return;
  const f32x4* p = (const f32x4*)(src + (size_t)li * 8);
  f32x4 a = p[0], b = p[1];
  u32x4 o = {pk(a[0], a[1]), pk(a[2], a[3]), pk(b[0], b[1]), pk(b[2], b[3])};
  *(u32x4*)(dst + (size_t)li * 8) = o;
}

struct GemmP {
  const u16* A; const u16* B;
  int lda, ldb, K;
  long bsA, bsB, bsC;       // per-blockIdx.z element strides
  int ldc;
  u16* Cb;                  // EPI 2/3/4 (f16 store)
  const float* bias;        // EPI 2,3
  const u16* resid;         // EPI 3 (h, f16, ld 512)
  u16* qk; u16* vT;         // EPI 1 (proj split)
  float scale;              // EPI 1
};

// =======================================================================
// 128x128 tile, BK=64, 4 waves (2x2), 16x16x32 f16 MFMA.
// COVERED-STAGING double-buffer (T3-minimum 2-phase), single barrier/K-tile:
//   __syncthreads  (buf[cur] staged; the vmcnt(0) drain the compiler emits
//                   here is covered by the PREVIOUS iteration's 16 ds_read
//                   + 32 MFMA issued after its stage)
//   stage(buf[cur^1])   <- issued FIRST, latency hidden under this tile
//   16 ds_read_b128 + 32 MFMA on buf[cur]
// Swizzle/fragment layout identical to the measured-0-conflict round-4
// kernel (16x16 m89 layout). LDS 64KB = 2 x (A 16K + B 16K).
// EPI: 1 = proj split (q*SC | k | vT), 2 = +bias relu f16 (ff1),
//      3 = +bias +resid f16 (ff2), 4 = plain f16 (scores, PV).
// =======================================================================
template <int EPI>
__global__ __launch_bounds__(256) void gemm_bt(GemmP p) {
  __shared__ __align__(16) char lds[65536];
  const int tid = threadIdx.x;
  const int lane = tid & 63;
  const int wave = tid >> 6;
  const int wm = wave >> 1, wn = wave & 1;
  const int bn0 = blockIdx.x * 128;
  const int bm0 = blockIdx.y * 128;
  const int z = blockIdx.z;

  // --- staging state: 4 A-chunks + 4 B-chunks per thread, ptr-advance ---
  const u16* gA[4]; const u16* gB[4];
  int ldsA[4], ldsB[4];
  {
    const u16* Ab = p.A + (long)z * p.bsA + (long)bm0 * p.lda;
    const u16* Bb = p.B + (long)z * p.bsB + (long)bn0 * p.ldb;
#pragma unroll
    for (int i = 0; i < 4; ++i) {
      int ch = i * 256 + tid;
      int row = ch >> 3, s = ch & 7;
      int ks = ((s ^ (row & 7)) << 3);  // inverse-swizzled global source
      gA[i] = Ab + (long)row * p.lda + ks;
      gB[i] = Bb + (long)row * p.ldb + ks;
      ldsA[i] = ch * 16;
      ldsB[i] = 16384 + ch * 16;
    }
  }
  auto stage = [&](int buf) {
    char* dst = lds + buf * 32768;
#pragma unroll
    for (int i = 0; i < 4; ++i) {
      __builtin_amdgcn_global_load_lds(
          (const __attribute__((address_space(1))) u32*)gA[i],
          (__attribute__((address_space(3))) u32*)(dst + ldsA[i]), 16, 0, 0);
      gA[i] += 64;
    }
#pragma unroll
    for (int i = 0; i < 4; ++i) {
      __builtin_amdgcn_global_load_lds(
          (const __attribute__((address_space(1))) u32*)gB[i],
          (__attribute__((address_space(3))) u32*)(dst + ldsB[i]), 16, 0, 0);
      gB[i] += 64;
    }
  };

  // --- LDS fragment read offsets (2 K-halves x 4 frags), buf-relative ---
  int ao[2][4], bo[2][4];
#pragma unroll
  for (int h = 0; h < 2; ++h) {
#pragma unroll
    for (int i = 0; i < 4; ++i) {
      int rA = wm * 64 + i * 16 + (lane & 15);
      ao[h][i] = rA * 128 + ((((h << 2) | (lane >> 4)) ^ (rA & 7)) << 4);
      int rB = wn * 64 + i * 16 + (lane & 15);
      bo[h][i] = 16384 + rB * 128 + ((((h << 2) | (lane >> 4)) ^ (rB & 7)) << 4);
    }
  }

  f32x4 acc[4][4] = {};
  stage(0);
  const int nk = p.K >> 6;
  int cur = 0;
  for (int kt = 0; kt < nk; ++kt) {
    __syncthreads();                  // buf[cur] landed; drain covered by prev tile
    if (kt + 1 < nk) stage(cur ^ 1);  // issue next tile FIRST
    const char* base = lds + cur * 32768;
#pragma unroll
    for (int h = 0; h < 2; ++h) {
      f16x8 av[4], bv[4];
#pragma unroll
      for (int i = 0; i < 4; ++i) av[i] = *(const f16x8*)(base + ao[h][i]);
#pragma unroll
      for (int j = 0; j < 4; ++j) bv[j] = *(const f16x8*)(base + bo[h][j]);
#pragma unroll
      for (int i = 0; i < 4; ++i)
#pragma unroll
        for (int j = 0; j < 4; ++j)
          acc[i][j] = __builtin_amdgcn_mfma_f32_16x16x32_f16(av[i], bv[j], acc[i][j], 0, 0, 0);
    }
    cur ^= 1;
  }

  // epilogue: C row = (lane>>4)*4+reg, col = lane&15 (m89 layout)
#pragma unroll
  for (int i = 0; i < 4; ++i) {
#pragma unroll
    for (int j = 0; j < 4; ++j) {
      int mb = bm0 + wm * 64 + i * 16 + ((lane >> 4) << 2);
      int n = bn0 + wn * 64 + j * 16 + (lane & 15);
      if constexpr (EPI == 1) {  // proj split into q*SCALE | k | vT
        int b = mb >> 11, l0 = mb & 2047;
        if (n < EDIM) {
          u16* dst = p.qk + (long)b * 4194304 + (long)l0 * 1024 + n;
#pragma unroll
          for (int r = 0; r < 4; ++r) dst[r * 1024] = f2h(acc[i][j][r] * p.scale);
        } else if (n < 2 * EDIM) {
          u16* dst = p.qk + (long)b * 4194304 + 2097152 + (long)l0 * 1024 + (n - EDIM);
#pragma unroll
          for (int r = 0; r < 4; ++r) dst[r * 1024] = f2h(acc[i][j][r]);
        } else {  // vT[b][n-2048][l0..l0+3] -- 8B packed store
          u16* dst = p.vT + (long)b * 1048576 + (long)(n - 2 * EDIM) * 2048 + l0;
          u32x2 w = {pk(acc[i][j][0], acc[i][j][1]), pk(acc[i][j][2], acc[i][j][3])};
          *(u32x2*)dst = w;
        }
      } else if constexpr (EPI == 2) {  // +bias, relu, f16 out (ff1)
        u16* dst = p.Cb + (long)mb * p.ldc + n;
        float bias = p.bias[n];
#pragma unroll
        for (int r = 0; r < 4; ++r) dst[(long)r * p.ldc] = f2h(fmaxf(acc[i][j][r] + bias, 0.f));
      } else if constexpr (EPI == 3) {  // +bias +resid, f16 out (ff2), ld 512
        float bias = p.bias[n];
        u16* dst = p.Cb + (long)mb * 512 + n;
        const u16* rs = p.resid + (long)mb * 512 + n;
#pragma unroll
        for (int r = 0; r < 4; ++r) dst[r * 512] = f2h(acc[i][j][r] + bias + h2f(rs[r * 512]));
      } else {  // EPI 4: plain f16 (scores, PV)
        u16* dst = p.Cb + (long)z * p.bsC + (long)mb * p.ldc + n;
#pragma unroll
        for (int r = 0; r < 4; ++r) dst[(long)r * p.ldc] = f2h(acc[i][j][r]);
      }
    }
  }
}

// ---------- row softmax: 1 block / row of 2048 f16 -> f16 weights ----------
__global__ __launch_bounds__(256) void softmax_rows(const u16* __restrict__ S,
                                                    u16* __restrict__ W, int b0) {
  int r = blockIdx.x;
  int z = r >> 11, l = r & 2047;
  int tid = threadIdx.x, lane = tid & 63, wv = tid >> 6;
  const u16* x = S + (long)r * 2048 + tid * 8;
  u32x4 raw = *(const u32x4*)x;
  float e[8];
#pragma unroll
  for (int q = 0; q < 4; ++q) {
    e[2 * q] = h2f((u16)(raw[q] & 0xffff));
    e[2 * q + 1] = h2f((u16)(raw[q] >> 16));
  }
  float m = e[0];
#pragma unroll
  for (int q = 1; q < 8; ++q) m = fmaxf(m, e[q]);
#pragma unroll
  for (int off = 32; off; off >>= 1) m = fmaxf(m, __shfl_xor(m, off));
  __shared__ float red[8];
  if (lane == 0) red[wv] = m;
  __syncthreads();
  m = fmaxf(fmaxf(red[0], red[1]), fmaxf(red[2], red[3]));
  float s = 0.f;
#pragma unroll
  for (int q = 0; q < 8; ++q) { e[q] = __expf(e[q] - m); s += e[q]; }
#pragma unroll
  for (int off = 32; off; off >>= 1) s += __shfl_xor(s, off);
  if (lane == 0) red[4 + wv] = s;
  __syncthreads();
  s = red[4] + red[5] + red[6] + red[7];
  float inv = 1.f / s;
  u32x4 o = {pk(e[0] * inv, e[1] * inv), pk(e[2] * inv, e[3] * inv),
             pk(e[4] * inv, e[5] * inv), pk(e[6] * inv, e[7] * inv)};
  *(u32x4*)(W + (long)(b0 + z) * 4194304 + (long)l * 2048 + tid * 8) = o;
}

// ---------- LayerNorm over 512, wave per row ----------
template <int INF16, int OUTF16>
__global__ __launch_bounds__(256) void ln_rows(const void* __restrict__ X,
                                               const float* __restrict__ g,
                                               const float* __restrict__ bb,
                                               void* __restrict__ out) {
  int row = blockIdx.x * 4 + (threadIdx.x >> 6);
  int lane = threadIdx.x & 63;
  float v[8];
  if constexpr (INF16) {
    u32x4 raw = *(const u32x4*)((const u16*)X + (long)row * 512 + lane * 8);
#pragma unroll
    for (int q = 0; q < 4; ++q) {
      v[2 * q] = h2f((u16)(raw[q] & 0xffff));
      v[2 * q + 1] = h2f((u16)(raw[q] >> 16));
    }
  } else {
    const float* x = (const float*)X + (long)row * 512 + lane * 8;
    f32x4 a = *(const f32x4*)x, b = *(const f32x4*)(x + 4);
#pragma unroll
    for (int q = 0; q < 4; ++q) { v[q] = a[q]; v[4 + q] = b[q]; }
  }
  float s = 0.f, sq = 0.f;
#pragma unroll
  for (int q = 0; q < 8; ++q) { s += v[q]; sq += v[q] * v[q]; }
#pragma unroll
  for (int off = 32; off; off >>= 1) {
    s += __shfl_xor(s, off);
    sq += __shfl_xor(sq, off);
  }
  float mean = s * (1.f / 512.f);
  float var = sq * (1.f / 512.f) - mean * mean;
  float rstd = rsqrtf(var + 1e-5f);
  f32x4 g0 = *(const f32x4*)(g + lane * 8), g1v = *(const f32x4*)(g + lane * 8 + 4);
  f32x4 b0 = *(const f32x4*)(bb + lane * 8), b1v = *(const f32x4*)(bb + lane * 8 + 4);
  float o[8];
#pragma unroll
  for (int q = 0; q < 4; ++q) o[q] = (v[q] - mean) * rstd * g0[q] + b0[q];
#pragma unroll
  for (int q = 0; q < 4; ++q) o[4 + q] = (v[4 + q] - mean) * rstd * g1v[q] + b1v[q];
  if constexpr (OUTF16) {
    u32x4 pkd = {pk(o[0], o[1]), pk(o[2], o[3]), pk(o[4], o[5]), pk(o[6], o[7])};
    *(u32x4*)((u16*)out + (long)row * 512 + lane * 8) = pkd;
  } else {
    float* dst = (float*)out + (long)row * 512 + lane * 8;
    *(f32x4*)dst = (f32x4){o[0], o[1], o[2], o[3]};
    *(f32x4*)(dst + 4) = (f32x4){o[4], o[5], o[6], o[7]};
  }
}

// ---------- launch ----------
extern "C" void kernel_launch(void* const* d_in, const int* in_sizes, int n_in,
                              void* d_out, int out_size, void* d_ws, size_t ws_size,
                              hipStream_t stream) {
  const float* x = (const float*)d_in[0];
  const float* wp = (const float*)d_in[1];
  const float* w1 = (const float*)d_in[2];
  const float* b1 = (const float*)d_in[3];
  const float* w2 = (const float*)d_in[4];
  const float* b2 = (const float*)d_in[5];
  const float* g1 = (const float*)d_in[6];
  const float* be1 = (const float*)d_in[7];
  const float* g2 = (const float*)d_in[8];
  const float* be2 = (const float*)d_in[9];

  char* ws = (char*)d_ws;
  size_t off = 0;
  auto alloc = [&](size_t bytes) {
    char* p = ws + off;
    off += (bytes + 255) & ~(size_t)255;
    return p;
  };
  u16* wpb = (u16*)alloc(2560 * 1024 * 2);
  u16* w1b = (u16*)alloc(2048 * 512 * 2);
  u16* w2b = (u16*)alloc(512 * 2048 * 2);
  char* xb_region = alloc(33554432);            // x f16 -> attn_out f16
  u16* qk = (u16*)alloc(67108864);              // [q|k] f16 -> attnw -> ff1
  u16* vT = (u16*)alloc(16777216);              // v transposed f16
  u16* hb = (u16*)alloc(16777216);              // h f16
  int bpl = (ws_size >= off + (size_t)67108864) ? 8 : 4;
  char* sc_region = alloc((size_t)bpl * 2048 * 2048 * 2);
  if (off > ws_size) return;

  u16* xb = (u16*)xb_region;
  u16* attn16 = (u16*)xb_region;
  u16* scores = (u16*)sc_region;
  u16* y16 = (u16*)sc_region;
  u16* ff1 = qk;

  const float SC = (float)(0.03125 * 2.0 * 7.6246189861593985);

  cvt_all<<<dim3(10496), dim3(256), 0, stream>>>(x, xb, wp, wpb, w1, w1b, w2, w2b);

  {  // proj: (16384x1024) @ (2560x1024)^T, split epilogue
    GemmP p{};
    p.A = xb; p.lda = 1024; p.B = wpb; p.ldb = 1024; p.K = 1024;
    p.qk = qk; p.vT = vT; p.scale = SC;
    gemm_bt<1><<<dim3(20, 128, 1), 256, 0, stream>>>(p);
  }

  for (int it = 0; it < 8 / bpl; ++it) {  // scores + softmax
    int b0 = it * bpl;
    GemmP p{};
    p.A = qk + (long)b0 * 4194304; p.lda = 1024; p.bsA = 4194304;
    p.B = qk + (long)b0 * 4194304 + 2097152; p.ldb = 1024; p.bsB = 4194304;
    p.K = 1024; p.Cb = scores; p.ldc = 2048; p.bsC = 4194304;
    gemm_bt<4><<<dim3(16, 16, bpl), 256, 0, stream>>>(p);
    softmax_rows<<<dim3(bpl * 2048), dim3(256), 0, stream>>>(scores, qk, b0);
  }

  {  // PV: attnw(2048x2048) @ vT(512x2048)^T per batch -> f16
    GemmP p{};
    p.A = qk; p.lda = 2048; p.bsA = 4194304;
    p.B = vT; p.ldb = 2048; p.bsB = 1048576;
    p.K = 2048; p.Cb = attn16; p.ldc = 512; p.bsC = 1048576;
    gemm_bt<4><<<dim3(4, 16, 8), 256, 0, stream>>>(p);
  }

  ln_rows<1, 1><<<dim3(4096), dim3(256), 0, stream>>>(attn16, g1, be1, hb);

  {  // ff1: h(16384x512) @ w1(2048x512)^T, +b1 relu -> f16
    GemmP p{};
    p.A = hb; p.lda = 512; p.B = w1b; p.ldb = 512; p.K = 512;
    p.Cb = ff1; p.ldc = 2048; p.bias = b1;
    gemm_bt<2><<<dim3(16, 128, 1), 256, 0, stream>>>(p);
  }

  {  // ff2: ff1(16384x2048) @ w2(512x2048)^T, +b2 +h -> f16
    GemmP p{};
    p.A = ff1; p.lda = 2048; p.B = w2b; p.ldb = 2048; p.K = 2048;
    p.Cb = y16; p.bias = b2; p.resid = hb;
    gemm_bt<3><<<dim3(4, 128, 1), 256, 0, stream>>>(p);
  }

  ln_rows<1, 0><<<dim3(4096), dim3(256), 0, stream>>>(y16, g2, be2, (float*)d_out);
}

// Round 9
// 376.547 us; speedup vs baseline: 1.0725x; 1.0068x over previous
//
#include <hip/hip_runtime.h>
#include <hip/hip_bf16.h>

// ---------- types ----------
typedef unsigned short u16;
typedef unsigned int u32;
typedef float f32x4 __attribute__((ext_vector_type(4)));
typedef _Float16 f16x8 __attribute__((ext_vector_type(8)));
typedef u32 u32x4 __attribute__((ext_vector_type(4)));
typedef u32 u32x2 __attribute__((ext_vector_type(2)));

#define SEQ 2048
#define EDIM 1024

__device__ __forceinline__ u16 f2h(float f) {
  _Float16 h = (_Float16)f;
  return __builtin_bit_cast(u16, h);
}
__device__ __forceinline__ float h2f(u16 u) {
  return (float)__builtin_bit_cast(_Float16, u);
}
__device__ __forceinline__ u32 pk(float a, float b) {
  return (u32)f2h(a) | ((u32)f2h(b) << 16);
}

// ---------- fused fp32 -> fp16 convert for all 4 inputs, 8 elems/thread ----
#define N_X  2097152
#define N_WP 327680
#define N_W1 131072
#define N_W2 131072
__global__ __launch_bounds__(256) void cvt_all(const float* __restrict__ x, u16* __restrict__ xb,
                                               const float* __restrict__ wp, u16* __restrict__ wpb,
                                               const float* __restrict__ w1, u16* __restrict__ w1b,
                                               const float* __restrict__ w2, u16* __restrict__ w2b) {
  int i = blockIdx.x * 256 + threadIdx.x;
  const float* src; u16* dst; int li;
  if (i < N_X) { src = x; dst = xb; li = i; }
  else if (i < N_X + N_WP) { src = wp; dst = wpb; li = i - N_X; }
  else if (i < N_X + N_WP + N_W1) { src = w1; dst = w1b; li = i - N_X - N_WP; }
  else if (i < N_X + N_WP + N_W1 + N_W2) { src = w2; dst = w2b; li = i - N_X - N_WP - N_W1; }
  else return;
  const f32x4* p = (const f32x4*)(src + (size_t)li * 8);
  f32x4 a = p[0], b = p[1];
  u32x4 o = {pk(a[0], a[1]), pk(a[2], a[3]), pk(b[0], b[1]), pk(b[2], b[3])};
  *(u32x4*)(dst + (size_t)li * 8) = o;
}

struct GemmP {
  const u16* A; const u16* B;
  int lda, ldb, K;
  long bsA, bsB, bsC;       // per-blockIdx.z element strides
  int ldc;
  u16* Cb;                  // f16 store
  const float* bias;        // EPI 2,3
  const u16* resid;         // EPI 3 (h, f16, ld 512)
  u16* qk; u16* vT;         // EPI 1 (proj split)
  float scale;              // EPI 1
};

// =======================================================================
// 256x256 tile, BK=64, 8 waves (2Mx4N, 128x64/wave), 16x16x32 f16 MFMA.
// Round-8's COVERED-STAGING 2-phase loop ported to 256^2 geometry:
//   __syncthreads -> stage(other buf) FIRST -> 24 ds_read + 64 MFMA.
// Staged bytes per FLOP halved vs 128^2; per-CU per K-tile: MFMA ~2483cyc
// vs LDS ~2048cyc -> MFMA-bound. LDS 128KB = 2 x (A 32K + B 32K).
// Same 0-conflict swizzle: row&7==lane&7 for all fragment rows, so all
// A-reads = baseA(h) + m*2048, B-reads = baseB(h) + j*2048 (imm offsets).
// EPI: 1 = proj split (q*SC | k | vT), 2 = +bias relu f16 (ff1),
//      4 = plain f16 (scores).
// =======================================================================
template <int EPI>
__global__ __launch_bounds__(512, 2) void gemm256(GemmP p) {
  __shared__ __align__(16) char lds[131072];
  const int tid = threadIdx.x;
  const int lane = tid & 63;
  const int wave = tid >> 6;
  const int wm = wave >> 2, wn = wave & 3;   // 2 x 4 waves
  const int bn0 = blockIdx.x * 256;
  const int bm0 = blockIdx.y * 256;
  const int z = blockIdx.z;

  // --- staging: A = 256 rows x 8 slots(16B) = 2048 chunks; B same.
  //     thread handles chunks {tid + i*512} for A and B (8 gload_lds/K-tile)
  const u16* gA[4]; const u16* gB[4];
  int ldsA[4], ldsB[4];
  {
    const u16* Ab = p.A + (long)z * p.bsA + (long)bm0 * p.lda;
    const u16* Bb = p.B + (long)z * p.bsB + (long)bn0 * p.ldb;
#pragma unroll
    for (int i = 0; i < 4; ++i) {
      int ch = i * 512 + tid;
      int row = ch >> 3, s = ch & 7;
      int ks = ((s ^ (row & 7)) << 3);  // inverse-swizzled global source
      gA[i] = Ab + (long)row * p.lda + ks;
      gB[i] = Bb + (long)row * p.ldb + ks;
      ldsA[i] = ch * 16;
      ldsB[i] = 32768 + ch * 16;
    }
  }
  auto stage = [&](int buf) {
    char* dst = lds + buf * 65536;
#pragma unroll
    for (int i = 0; i < 4; ++i) {
      __builtin_amdgcn_global_load_lds(
          (const __attribute__((address_space(1))) u32*)gA[i],
          (__attribute__((address_space(3))) u32*)(dst + ldsA[i]), 16, 0, 0);
      gA[i] += 64;
    }
#pragma unroll
    for (int i = 0; i < 4; ++i) {
      __builtin_amdgcn_global_load_lds(
          (const __attribute__((address_space(1))) u32*)gB[i],
          (__attribute__((address_space(3))) u32*)(dst + ldsB[i]), 16, 0, 0);
      gB[i] += 64;
    }
  };

  // --- fragment read bases (h=0,1): row&7 == lane&7 for every frag row ---
  int abase[2], bbase[2];
  {
    int rA = wm * 128 + (lane & 15);
    int sA = (lane >> 4) ^ (lane & 7);
    abase[0] = rA * 128 + (sA << 4);
    abase[1] = abase[0] ^ 64;          // slot ^= 4  ->  byte ^= 64
    int rB = wn * 64 + (lane & 15);
    int sB = (lane >> 4) ^ (lane & 7);
    bbase[0] = 32768 + rB * 128 + (sB << 4);
    bbase[1] = bbase[0] ^ 64;
  }

  f32x4 acc[8][4] = {};
  stage(0);
  const int nk = p.K >> 6;
  int cur = 0;
  for (int kt = 0; kt < nk; ++kt) {
    __syncthreads();                  // buf[cur] landed; drain covered by prev tile
    if (kt + 1 < nk) stage(cur ^ 1);  // issue next tile FIRST
    const char* base = lds + cur * 65536;
#pragma unroll
    for (int h = 0; h < 2; ++h) {
      f16x8 av[8], bv[4];
#pragma unroll
      for (int m = 0; m < 8; ++m) av[m] = *(const f16x8*)(base + abase[h] + m * 2048);
#pragma unroll
      for (int j = 0; j < 4; ++j) bv[j] = *(const f16x8*)(base + bbase[h] + j * 2048);
#pragma unroll
      for (int m = 0; m < 8; ++m)
#pragma unroll
        for (int j = 0; j < 4; ++j)
          acc[m][j] = __builtin_amdgcn_mfma_f32_16x16x32_f16(av[m], bv[j], acc[m][j], 0, 0, 0);
    }
    cur ^= 1;
  }

  // epilogue: C row = (lane>>4)*4+reg, col = lane&15 (m89 layout)
#pragma unroll
  for (int i = 0; i < 8; ++i) {
#pragma unroll
    for (int j = 0; j < 4; ++j) {
      int mb = bm0 + wm * 128 + i * 16 + ((lane >> 4) << 2);
      int n = bn0 + wn * 64 + j * 16 + (lane & 15);
      if constexpr (EPI == 1) {  // proj split into q*SCALE | k | vT
        int b = mb >> 11, l0 = mb & 2047;
        if (n < EDIM) {
          u16* dst = p.qk + (long)b * 4194304 + (long)l0 * 1024 + n;
#pragma unroll
          for (int r = 0; r < 4; ++r) dst[r * 1024] = f2h(acc[i][j][r] * p.scale);
        } else if (n < 2 * EDIM) {
          u16* dst = p.qk + (long)b * 4194304 + 2097152 + (long)l0 * 1024 + (n - EDIM);
#pragma unroll
          for (int r = 0; r < 4; ++r) dst[r * 1024] = f2h(acc[i][j][r]);
        } else {  // vT[b][n-2048][l0..l0+3] -- 8B packed store
          u16* dst = p.vT + (long)b * 1048576 + (long)(n - 2 * EDIM) * 2048 + l0;
          u32x2 w = {pk(acc[i][j][0], acc[i][j][1]), pk(acc[i][j][2], acc[i][j][3])};
          *(u32x2*)dst = w;
        }
      } else if constexpr (EPI == 2) {  // +bias, relu, f16 out (ff1)
        u16* dst = p.Cb + (long)mb * p.ldc + n;
        float bias = p.bias[n];
#pragma unroll
        for (int r = 0; r < 4; ++r) dst[(long)r * p.ldc] = f2h(fmaxf(acc[i][j][r] + bias, 0.f));
      } else {  // EPI 4: plain f16 (scores)
        u16* dst = p.Cb + (long)z * p.bsC + (long)mb * p.ldc + n;
#pragma unroll
        for (int r = 0; r < 4; ++r) dst[(long)r * p.ldc] = f2h(acc[i][j][r]);
      }
    }
  }
}

// =======================================================================
// 128x128 tile covered 2-phase kernel (round-8, proven) — PV / ff2.
// =======================================================================
template <int EPI>
__global__ __launch_bounds__(256) void gemm_bt(GemmP p) {
  __shared__ __align__(16) char lds[65536];
  const int tid = threadIdx.x;
  const int lane = tid & 63;
  const int wave = tid >> 6;
  const int wm = wave >> 1, wn = wave & 1;
  const int bn0 = blockIdx.x * 128;
  const int bm0 = blockIdx.y * 128;
  const int z = blockIdx.z;

  const u16* gA[4]; const u16* gB[4];
  int ldsA[4], ldsB[4];
  {
    const u16* Ab = p.A + (long)z * p.bsA + (long)bm0 * p.lda;
    const u16* Bb = p.B + (long)z * p.bsB + (long)bn0 * p.ldb;
#pragma unroll
    for (int i = 0; i < 4; ++i) {
      int ch = i * 256 + tid;
      int row = ch >> 3, s = ch & 7;
      int ks = ((s ^ (row & 7)) << 3);
      gA[i] = Ab + (long)row * p.lda + ks;
      gB[i] = Bb + (long)row * p.ldb + ks;
      ldsA[i] = ch * 16;
      ldsB[i] = 16384 + ch * 16;
    }
  }
  auto stage = [&](int buf) {
    char* dst = lds + buf * 32768;
#pragma unroll
    for (int i = 0; i < 4; ++i) {
      __builtin_amdgcn_global_load_lds(
          (const __attribute__((address_space(1))) u32*)gA[i],
          (__attribute__((address_space(3))) u32*)(dst + ldsA[i]), 16, 0, 0);
      gA[i] += 64;
    }
#pragma unroll
    for (int i = 0; i < 4; ++i) {
      __builtin_amdgcn_global_load_lds(
          (const __attribute__((address_space(1))) u32*)gB[i],
          (__attribute__((address_space(3))) u32*)(dst + ldsB[i]), 16, 0, 0);
      gB[i] += 64;
    }
  };

  int ao[2][4], bo[2][4];
#pragma unroll
  for (int h = 0; h < 2; ++h) {
#pragma unroll
    for (int i = 0; i < 4; ++i) {
      int rA = wm * 64 + i * 16 + (lane & 15);
      ao[h][i] = rA * 128 + ((((h << 2) | (lane >> 4)) ^ (rA & 7)) << 4);
      int rB = wn * 64 + i * 16 + (lane & 15);
      bo[h][i] = 16384 + rB * 128 + ((((h << 2) | (lane >> 4)) ^ (rB & 7)) << 4);
    }
  }

  f32x4 acc[4][4] = {};
  stage(0);
  const int nk = p.K >> 6;
  int cur = 0;
  for (int kt = 0; kt < nk; ++kt) {
    __syncthreads();
    if (kt + 1 < nk) stage(cur ^ 1);
    const char* base = lds + cur * 32768;
#pragma unroll
    for (int h = 0; h < 2; ++h) {
      f16x8 av[4], bv[4];
#pragma unroll
      for (int i = 0; i < 4; ++i) av[i] = *(const f16x8*)(base + ao[h][i]);
#pragma unroll
      for (int j = 0; j < 4; ++j) bv[j] = *(const f16x8*)(base + bo[h][j]);
#pragma unroll
      for (int i = 0; i < 4; ++i)
#pragma unroll
        for (int j = 0; j < 4; ++j)
          acc[i][j] = __builtin_amdgcn_mfma_f32_16x16x32_f16(av[i], bv[j], acc[i][j], 0, 0, 0);
    }
    cur ^= 1;
  }

#pragma unroll
  for (int i = 0; i < 4; ++i) {
#pragma unroll
    for (int j = 0; j < 4; ++j) {
      int mb = bm0 + wm * 64 + i * 16 + ((lane >> 4) << 2);
      int n = bn0 + wn * 64 + j * 16 + (lane & 15);
      if constexpr (EPI == 3) {  // +bias +resid, f16 out (ff2), ld 512
        float bias = p.bias[n];
        u16* dst = p.Cb + (long)mb * 512 + n;
        const u16* rs = p.resid + (long)mb * 512 + n;
#pragma unroll
        for (int r = 0; r < 4; ++r) dst[r * 512] = f2h(acc[i][j][r] + bias + h2f(rs[r * 512]));
      } else {  // EPI 4: plain f16 (PV)
        u16* dst = p.Cb + (long)z * p.bsC + (long)mb * p.ldc + n;
#pragma unroll
        for (int r = 0; r < 4; ++r) dst[(long)r * p.ldc] = f2h(acc[i][j][r]);
      }
    }
  }
}

// ---------- row softmax: 1 block / row of 2048 f16 -> f16 weights ----------
__global__ __launch_bounds__(256) void softmax_rows(const u16* __restrict__ S,
                                                    u16* __restrict__ W, int b0) {
  int r = blockIdx.x;
  int z = r >> 11, l = r & 2047;
  int tid = threadIdx.x, lane = tid & 63, wv = tid >> 6;
  const u16* x = S + (long)r * 2048 + tid * 8;
  u32x4 raw = *(const u32x4*)x;
  float e[8];
#pragma unroll
  for (int q = 0; q < 4; ++q) {
    e[2 * q] = h2f((u16)(raw[q] & 0xffff));
    e[2 * q + 1] = h2f((u16)(raw[q] >> 16));
  }
  float m = e[0];
#pragma unroll
  for (int q = 1; q < 8; ++q) m = fmaxf(m, e[q]);
#pragma unroll
  for (int off = 32; off; off >>= 1) m = fmaxf(m, __shfl_xor(m, off));
  __shared__ float red[8];
  if (lane == 0) red[wv] = m;
  __syncthreads();
  m = fmaxf(fmaxf(red[0], red[1]), fmaxf(red[2], red[3]));
  float s = 0.f;
#pragma unroll
  for (int q = 0; q < 8; ++q) { e[q] = __expf(e[q] - m); s += e[q]; }
#pragma unroll
  for (int off = 32; off; off >>= 1) s += __shfl_xor(s, off);
  if (lane == 0) red[4 + wv] = s;
  __syncthreads();
  s = red[4] + red[5] + red[6] + red[7];
  float inv = 1.f / s;
  u32x4 o = {pk(e[0] * inv, e[1] * inv), pk(e[2] * inv, e[3] * inv),
             pk(e[4] * inv, e[5] * inv), pk(e[6] * inv, e[7] * inv)};
  *(u32x4*)(W + (long)(b0 + z) * 4194304 + (long)l * 2048 + tid * 8) = o;
}

// ---------- LayerNorm over 512, wave per row ----------
template <int INF16, int OUTF16>
__global__ __launch_bounds__(256) void ln_rows(const void* __restrict__ X,
                                               const float* __restrict__ g,
                                               const float* __restrict__ bb,
                                               void* __restrict__ out) {
  int row = blockIdx.x * 4 + (threadIdx.x >> 6);
  int lane = threadIdx.x & 63;
  float v[8];
  if constexpr (INF16) {
    u32x4 raw = *(const u32x4*)((const u16*)X + (long)row * 512 + lane * 8);
#pragma unroll
    for (int q = 0; q < 4; ++q) {
      v[2 * q] = h2f((u16)(raw[q] & 0xffff));
      v[2 * q + 1] = h2f((u16)(raw[q] >> 16));
    }
  } else {
    const float* x = (const float*)X + (long)row * 512 + lane * 8;
    f32x4 a = *(const f32x4*)x, b = *(const f32x4*)(x + 4);
#pragma unroll
    for (int q = 0; q < 4; ++q) { v[q] = a[q]; v[4 + q] = b[q]; }
  }
  float s = 0.f, sq = 0.f;
#pragma unroll
  for (int q = 0; q < 8; ++q) { s += v[q]; sq += v[q] * v[q]; }
#pragma unroll
  for (int off = 32; off; off >>= 1) {
    s += __shfl_xor(s, off);
    sq += __shfl_xor(sq, off);
  }
  float mean = s * (1.f / 512.f);
  float var = sq * (1.f / 512.f) - mean * mean;
  float rstd = rsqrtf(var + 1e-5f);
  f32x4 g0 = *(const f32x4*)(g + lane * 8), g1v = *(const f32x4*)(g + lane * 8 + 4);
  f32x4 b0 = *(const f32x4*)(bb + lane * 8), b1v = *(const f32x4*)(bb + lane * 8 + 4);
  float o[8];
#pragma unroll
  for (int q = 0; q < 4; ++q) o[q] = (v[q] - mean) * rstd * g0[q] + b0[q];
#pragma unroll
  for (int q = 0; q < 4; ++q) o[4 + q] = (v[4 + q] - mean) * rstd * g1v[q] + b1v[q];
  if constexpr (OUTF16) {
    u32x4 pkd = {pk(o[0], o[1]), pk(o[2], o[3]), pk(o[4], o[5]), pk(o[6], o[7])};
    *(u32x4*)((u16*)out + (long)row * 512 + lane * 8) = pkd;
  } else {
    float* dst = (float*)out + (long)row * 512 + lane * 8;
    *(f32x4*)dst = (f32x4){o[0], o[1], o[2], o[3]};
    *(f32x4*)(dst + 4) = (f32x4){o[4], o[5], o[6], o[7]};
  }
}

// ---------- launch ----------
extern "C" void kernel_launch(void* const* d_in, const int* in_sizes, int n_in,
                              void* d_out, int out_size, void* d_ws, size_t ws_size,
                              hipStream_t stream) {
  const float* x = (const float*)d_in[0];
  const float* wp = (const float*)d_in[1];
  const float* w1 = (const float*)d_in[2];
  const float* b1 = (const float*)d_in[3];
  const float* w2 = (const float*)d_in[4];
  const float* b2 = (const float*)d_in[5];
  const float* g1 = (const float*)d_in[6];
  const float* be1 = (const float*)d_in[7];
  const float* g2 = (const float*)d_in[8];
  const float* be2 = (const float*)d_in[9];

  char* ws = (char*)d_ws;
  size_t off = 0;
  auto alloc = [&](size_t bytes) {
    char* p = ws + off;
    off += (bytes + 255) & ~(size_t)255;
    return p;
  };
  u16* wpb = (u16*)alloc(2560 * 1024 * 2);
  u16* w1b = (u16*)alloc(2048 * 512 * 2);
  u16* w2b = (u16*)alloc(512 * 2048 * 2);
  char* xb_region = alloc(33554432);            // x f16 -> attn_out f16
  u16* qk = (u16*)alloc(67108864);              // [q|k] f16 -> attnw -> ff1
  u16* vT = (u16*)alloc(16777216);              // v transposed f16
  u16* hb = (u16*)alloc(16777216);              // h f16
  int bpl = (ws_size >= off + (size_t)67108864) ? 8 : 4;
  char* sc_region = alloc((size_t)bpl * 2048 * 2048 * 2);
  if (off > ws_size) return;

  u16* xb = (u16*)xb_region;
  u16* attn16 = (u16*)xb_region;
  u16* scores = (u16*)sc_region;
  u16* y16 = (u16*)sc_region;
  u16* ff1 = qk;

  const float SC = (float)(0.03125 * 2.0 * 7.6246189861593985);

  cvt_all<<<dim3(10496), dim3(256), 0, stream>>>(x, xb, wp, wpb, w1, w1b, w2, w2b);

  {  // proj: (16384x1024) @ (2560x1024)^T, split epilogue  [256^2 kernel]
    GemmP p{};
    p.A = xb; p.lda = 1024; p.B = wpb; p.ldb = 1024; p.K = 1024;
    p.qk = qk; p.vT = vT; p.scale = SC;
    gemm256<1><<<dim3(10, 64, 1), 512, 0, stream>>>(p);
  }

  for (int it = 0; it < 8 / bpl; ++it) {  // scores + softmax  [256^2 kernel]
    int b0 = it * bpl;
    GemmP p{};
    p.A = qk + (long)b0 * 4194304; p.lda = 1024; p.bsA = 4194304;
    p.B = qk + (long)b0 * 4194304 + 2097152; p.ldb = 1024; p.bsB = 4194304;
    p.K = 1024; p.Cb = scores; p.ldc = 2048; p.bsC = 4194304;
    gemm256<4><<<dim3(8, 8, bpl), 512, 0, stream>>>(p);
    softmax_rows<<<dim3(bpl * 2048), dim3(256), 0, stream>>>(scores, qk, b0);
  }

  {  // PV: attnw(2048x2048) @ vT(512x2048)^T per batch -> f16  [128^2 kernel]
    GemmP p{};
    p.A = qk; p.lda = 2048; p.bsA = 4194304;
    p.B = vT; p.ldb = 2048; p.bsB = 1048576;
    p.K = 2048; p.Cb = attn16; p.ldc = 512; p.bsC = 1048576;
    gemm_bt<4><<<dim3(4, 16, 8), 256, 0, stream>>>(p);
  }

  ln_rows<1, 1><<<dim3(4096), dim3(256), 0, stream>>>(attn16, g1, be1, hb);

  {  // ff1: h(16384x512) @ w1(2048x512)^T, +b1 relu -> f16  [256^2 kernel]
    GemmP p{};
    p.A = hb; p.lda = 512; p.B = w1b; p.ldb = 512; p.K = 512;
    p.Cb = ff1; p.ldc = 2048; p.bias = b1;
    gemm256<2><<<dim3(8, 64, 1), 512, 0, stream>>>(p);
  }

  {  // ff2: ff1(16384x2048) @ w2(512x2048)^T, +b2 +h -> f16  [128^2 kernel]
    GemmP p{};
    p.A = ff1; p.lda = 2048; p.B = w2b; p.ldb = 2048; p.K = 2048;
    p.Cb = y16; p.bias = b2; p.resid = hb;
    gemm_bt<3><<<dim3(4, 128, 1), 256, 0, stream>>>(p);
  }

  ln_rows<1, 0><<<dim3(4096), dim3(256), 0, stream>>>(y16, g2, be2, (float*)d_out);
}